// Round 8
// baseline (346.418 us; speedup 1.0000x reference)
//
#include <hip/hip_runtime.h>

#define BATCH 512
#define NI 1152
#define ND 8
#define NO 10
#define NE 16

constexpr int THREADS = 512;
constexpr int WAVES   = THREADS / 64;   // 8
constexpr int QUADS   = THREADS / 4;    // 128 i-rows per sweep
constexpr int ITEMS   = NI / QUADS;     // 9 (exact: 1152 = 128*9)
constexpr int BB      = 2;              // batch elements per block (W reuse)
constexpr int BPG     = BATCH / BB;     // 256 blocks per out-capsule
constexpr int REG_K   = 4;              // k-items held in fp32 registers
constexpr int LDS_K   = ITEMS - REG_K;  // 5 k-items in bf16 LDS

// Evolution: all-reg priors (BB>=2) -> RA pins 128 VGPR, 1 GB spill (r2-5).
// all-LDS fp32 -> 149 KB, 1 blk/CU, latency-bound (r6). all-LDS bf16 ->
// 75 KB, 2 blk/CU, 121 us, VALUBusy 51%, occupancy 42% -- still latency-
// limited by LDS occupancy cap (r7). This round: HYBRID split. k=0..3 in
// fp32 registers (32 VGPR, static idx), k=4..8 bf16 in LDS (40 KiB, total
// ~42 KiB -> 3 blocks/CU). VGPR ~96-104 -> 5 waves/SIMD (62% cap vs 50%).
// Register half skips pack/unpack + LDS traffic on 4/9 of sweep work, and
// keeps 4/9 of priors exact fp32 (absmax improves vs r7's 9.8e-3).
//
// Fused routing sweep (validated r5-7): no max-sub (|logit| <~ 40 << 88,
// softmax shift-invariant); one pass per iter accumulating sum(exp(l)*p),
// sum(exp(l)); divide at the end.

__device__ __forceinline__ unsigned int bf16_rne(float f) {
    const unsigned int u = __builtin_bit_cast(unsigned int, f);
    return (u + 0x7fffu + ((u >> 16) & 1u)) >> 16;
}
__device__ __forceinline__ float bf_lo(unsigned int u) {
    return __builtin_bit_cast(float, u << 16);
}
__device__ __forceinline__ float bf_hi(unsigned int u) {
    return __builtin_bit_cast(float, u & 0xffff0000u);
}

__global__ __launch_bounds__(THREADS, 4)
void caps_routing(const float* __restrict__ x,
                  const float* __restrict__ Wt,
                  float* __restrict__ out)
{
    const int o  = blockIdx.x / BPG;
    const int b0 = (blockIdx.x % BPG) * BB;

    __shared__ __align__(16) unsigned int pl[BB][LDS_K * QUADS][NE / 2]; // 40960 B
    __shared__ __align__(16) float red[BB][WAVES * 16];                  // 1 KiB
    __shared__ float sv[BB][16];
    __shared__ float rsum[BB][WAVES];

    const int t    = threadIdx.x;
    const int lane = t & 63;
    const int w    = t >> 6;
    const int e4   = t & 3;     // which float4 of the 16-wide E dim
    const int iq   = t >> 2;    // i-quad id, i = iq + k*QUADS

    const float* xb = x  + (size_t)b0 * (NI * ND);
    const float* Wo = Wt + (size_t)o * ((size_t)NI * ND * NE);

    float4 preg[BB][REG_K];  // fp32 priors, k < REG_K (32 VGPR)
    float  lg[BB][ITEMS];    // logits: quad-uniform, 18 regs
    float4 acc[BB];
#pragma unroll
    for (int bb = 0; bb < BB; ++bb) acc[bb] = make_float4(0.f, 0.f, 0.f, 0.f);

    // ---- priors = x[b,i,:] @ W[o,i,:,:] -> reg/LDS, fused iter-0 sum ----
#pragma unroll
    for (int k = 0; k < ITEMS; ++k) {
        const int i = iq + k * QUADS;
        float4 xa[BB], xc[BB];
#pragma unroll
        for (int bb = 0; bb < BB; ++bb) {
            const float* xr = xb + (size_t)bb * (NI * ND) + (size_t)i * ND;
            xa[bb] = *(const float4*)(xr);
            xc[bb] = *(const float4*)(xr + 4);
        }
        const float4* Wp = (const float4*)(Wo + (size_t)i * (ND * NE));
        float4 v[BB];
#pragma unroll
        for (int bb = 0; bb < BB; ++bb) v[bb] = make_float4(0.f, 0.f, 0.f, 0.f);
#define DSTEP(dd, FIELD, ARR) { const float4 wv = Wp[(dd)*4 + e4]; \
        _Pragma("unroll") \
        for (int bb = 0; bb < BB; ++bb) { const float xs = ARR[bb].FIELD; \
            v[bb].x += xs*wv.x; v[bb].y += xs*wv.y; \
            v[bb].z += xs*wv.z; v[bb].w += xs*wv.w; } }
        DSTEP(0, x, xa) DSTEP(1, y, xa) DSTEP(2, z, xa) DSTEP(3, w, xa)
        DSTEP(4, x, xc) DSTEP(5, y, xc) DSTEP(6, z, xc) DSTEP(7, w, xc)
#undef DSTEP
#pragma unroll
        for (int bb = 0; bb < BB; ++bb) {
            if (k < REG_K) {
                preg[bb][k] = v[bb];
            } else {
                uint2 pk;
                pk.x = bf16_rne(v[bb].x) | (bf16_rne(v[bb].y) << 16);
                pk.y = bf16_rne(v[bb].z) | (bf16_rne(v[bb].w) << 16);
                *(uint2*)&pl[bb][i - REG_K * QUADS][e4 * 2] = pk;
            }
            acc[bb].x += v[bb].x; acc[bb].y += v[bb].y;
            acc[bb].z += v[bb].z; acc[bb].w += v[bb].w;
        }
    }

    // ---- s0 = mean_i priors : reduce across quads (same e4) ----
#pragma unroll
    for (int bb = 0; bb < BB; ++bb) {
#pragma unroll
        for (int off = 4; off <= 32; off <<= 1) {
            acc[bb].x += __shfl_xor(acc[bb].x, off);
            acc[bb].y += __shfl_xor(acc[bb].y, off);
            acc[bb].z += __shfl_xor(acc[bb].z, off);
            acc[bb].w += __shfl_xor(acc[bb].w, off);
        }
        if (lane < 4) *(float4*)&red[bb][w * 16 + e4 * 4] = acc[bb];
    }
    __syncthreads();
    if (t < 16 * BB) {
        const int bb = t >> 4, e = t & 15;
        float s = 0.f;
#pragma unroll
        for (int q = 0; q < WAVES; ++q) s += red[bb][q * 16 + e];
        sv[bb][e] = s * (1.0f / (float)NI);
    }
    __syncthreads();

    // ---- squash(s0) -> outv (each thread keeps its e4 slice, all bb) ----
    float4 outv[BB];
#pragma unroll
    for (int bb = 0; bb < BB; ++bb) {
        float sq = 0.f;
#pragma unroll
        for (int e = 0; e < 16; ++e) { const float vv = sv[bb][e]; sq += vv * vv; }
        const float scale = sqrtf(sq) / (1.0f + sq);
        outv[bb].x = sv[bb][e4 * 4 + 0] * scale;
        outv[bb].y = sv[bb][e4 * 4 + 1] * scale;
        outv[bb].z = sv[bb][e4 * 4 + 2] * scale;
        outv[bb].w = sv[bb][e4 * 4 + 3] * scale;
    }

    // ---- routing iterations 1 and 2: single fused sweep per iteration ----
    for (int it = 1; it < 3; ++it) {
#pragma unroll
        for (int bb = 0; bb < BB; ++bb) {
            float4 pacc = make_float4(0.f, 0.f, 0.f, 0.f);
            float  lsum = 0.f;
#pragma unroll
            for (int k = 0; k < ITEMS; ++k) {
                float vx, vy, vz, vw;
                if (k < REG_K) {
                    vx = preg[bb][k].x; vy = preg[bb][k].y;
                    vz = preg[bb][k].z; vw = preg[bb][k].w;
                } else {
                    const int r = iq + (k - REG_K) * QUADS;
                    const uint2 pk = *(const uint2*)&pl[bb][r][e4 * 2];
                    vx = bf_lo(pk.x); vy = bf_hi(pk.x);
                    vz = bf_lo(pk.y); vw = bf_hi(pk.y);
                }
                float part = vx * outv[bb].x + vy * outv[bb].y
                           + vz * outv[bb].z + vw * outv[bb].w;
                part += __shfl_xor(part, 1);   // quad reduce: full dot over 16 E
                part += __shfl_xor(part, 2);
                const float l = (it == 1) ? part : (lg[bb][k] + part);
                lg[bb][k] = l;
                const float wgt = __expf(l);   // no max-sub: |l| <~ 40, safe
                pacc.x += wgt * vx; pacc.y += wgt * vy;
                pacc.z += wgt * vz; pacc.w += wgt * vw;
                lsum += wgt;                   // quad-uniform
            }
#pragma unroll
            for (int off = 4; off <= 32; off <<= 1) {
                pacc.x += __shfl_xor(pacc.x, off);
                pacc.y += __shfl_xor(pacc.y, off);
                pacc.z += __shfl_xor(pacc.z, off);
                pacc.w += __shfl_xor(pacc.w, off);
                lsum   += __shfl_xor(lsum, off);
            }
            if (lane < 4) *(float4*)&red[bb][w * 16 + e4 * 4] = pacc;
            if (lane == 0) rsum[bb][w] = lsum;
        }
        __syncthreads();
        if (t < 16 * BB) {
            const int bb = t >> 4, e = t & 15;
            float s = 0.f;
#pragma unroll
            for (int q = 0; q < WAVES; ++q) s += red[bb][q * 16 + e];
            float L = 0.f;
#pragma unroll
            for (int q = 0; q < WAVES; ++q) L += rsum[bb][q];
            sv[bb][e] = s / L;
        }
        __syncthreads();

        if (it == 1) {
            // squash -> new outv for the next sweep
#pragma unroll
            for (int bb = 0; bb < BB; ++bb) {
                float sq = 0.f;
#pragma unroll
                for (int e = 0; e < 16; ++e) { const float vv = sv[bb][e]; sq += vv * vv; }
                const float scale = sqrtf(sq) / (1.0f + sq);
                outv[bb].x = sv[bb][e4 * 4 + 0] * scale;
                outv[bb].y = sv[bb][e4 * 4 + 1] * scale;
                outv[bb].z = sv[bb][e4 * 4 + 2] * scale;
                outv[bb].w = sv[bb][e4 * 4 + 3] * scale;
            }
        }
    }

    // ---- final squash + write out[o, b0+bb, 0, 0, :] ----
    if (t < 16 * BB) {
        const int bb = t >> 4, e = t & 15;
        float sq = 0.f;
#pragma unroll
        for (int ee = 0; ee < 16; ++ee) { const float vv = sv[bb][ee]; sq += vv * vv; }
        const float scale = sqrtf(sq) / (1.0f + sq);
        out[((size_t)o * BATCH + b0 + bb) * NE + e] = sv[bb][e] * scale;
    }
}

extern "C" void kernel_launch(void* const* d_in, const int* in_sizes, int n_in,
                              void* d_out, int out_size, void* d_ws, size_t ws_size,
                              hipStream_t stream) {
    const float* x  = (const float*)d_in[0];
    const float* Wt = (const float*)d_in[1];
    float* outp = (float*)d_out;
    caps_routing<<<dim3(NO * BPG), dim3(THREADS), 0, stream>>>(x, Wt, outp);
}

// Round 11
// 216.606 us; speedup vs baseline: 1.5993x; 1.5993x over previous
//
#include <hip/hip_runtime.h>

#define BATCH 512
#define NI 1152
#define ND 8
#define NO 10
#define NE 16

constexpr int THREADS = 768;            // 12 waves; THREADS/4=192 divides 1152
constexpr int WAVES   = THREADS / 64;   // 12
constexpr int QUADS   = THREADS / 4;    // 192 i-rows per sweep
constexpr int ITEMS   = NI / QUADS;     // 6 (exact: 1152 = 192*6)
constexpr int BB      = 2;              // batch elements per block (W reuse)
constexpr int BPG     = BATCH / BB;     // 256 blocks per out-capsule

// Evolution: all-reg priors (BB>=2) -> RA spills ~1 GB/call (r2-5, r8: the
// allocator targets the 64/128-VGPR occupancy tiers and WILL spill arrays
// to hit them; launch_bounds minimums don't override). all-LDS fp32 ->
// 1 blk/CU, latency-bound (r6, 165us). all-LDS bf16 @512thr -> 75 KB,
// 2 blk/CU = 16 waves/CU, 121us, VALUBusy 51% -- still latency-bound,
// occupancy capped by LDS (r7).
//
// This round: SAME structure as r7, block size 512 -> 768 (12 waves).
// LDS/block unchanged (~74 KB -> 2 blocks/CU) but waves/CU: 16 -> 24
// (6/SIMD, 75% cap vs 50%): +50% latency hiding for free. Per-thread
// ITEMS drops 9 -> 6 (lg[2][6]: less pressure than r7, same 64-VGPR tier).
//
// Priors stored bf16 in LDS (storage only; all math fp32). Pack = RNE.
// Fused routing sweep (validated r5-r8, absmax 9.8e-3): no max-sub
// (|logit| <~ 40 << 88, softmax shift-invariant); one LDS pass per iter
// accumulating sum(exp(l)*p) and sum(exp(l)); divide at the end.

__device__ __forceinline__ unsigned int bf16_rne(float f) {
    const unsigned int u = __builtin_bit_cast(unsigned int, f);
    return (u + 0x7fffu + ((u >> 16) & 1u)) >> 16;
}
__device__ __forceinline__ float bf_lo(unsigned int u) {
    return __builtin_bit_cast(float, u << 16);
}
__device__ __forceinline__ float bf_hi(unsigned int u) {
    return __builtin_bit_cast(float, u & 0xffff0000u);
}

__global__ __launch_bounds__(THREADS, 4)
void caps_routing(const float* __restrict__ x,
                  const float* __restrict__ Wt,
                  float* __restrict__ out)
{
    const int o  = blockIdx.x / BPG;
    const int b0 = (blockIdx.x % BPG) * BB;

    __shared__ __align__(16) unsigned int pl[BB][NI][NE / 2]; // bf16x2, 73728 B
    __shared__ __align__(16) float red[BB][WAVES * 16];       // 1.5 KiB
    __shared__ float sv[BB][16];
    __shared__ float rsum[BB][WAVES];

    const int t    = threadIdx.x;
    const int lane = t & 63;
    const int w    = t >> 6;
    const int e4   = t & 3;     // which float4 of the 16-wide E dim
    const int iq   = t >> 2;    // i-quad id, i = iq + k*QUADS

    const float* xb = x  + (size_t)b0 * (NI * ND);
    const float* Wo = Wt + (size_t)o * ((size_t)NI * ND * NE);

    float lg[BB][ITEMS];     // logits: quad-uniform, 12 regs
    float4 acc[BB];
#pragma unroll
    for (int bb = 0; bb < BB; ++bb) acc[bb] = make_float4(0.f, 0.f, 0.f, 0.f);

    // ---- priors = x[b,i,:] @ W[o,i,:,:] -> LDS(bf16), fused iter-0 sum ----
#pragma unroll
    for (int k = 0; k < ITEMS; ++k) {
        const int i = iq + k * QUADS;
        float4 xa[BB], xc[BB];
#pragma unroll
        for (int bb = 0; bb < BB; ++bb) {
            const float* xr = xb + (size_t)bb * (NI * ND) + (size_t)i * ND;
            xa[bb] = *(const float4*)(xr);
            xc[bb] = *(const float4*)(xr + 4);
        }
        const float4* Wp = (const float4*)(Wo + (size_t)i * (ND * NE));
        float4 v[BB];
#pragma unroll
        for (int bb = 0; bb < BB; ++bb) v[bb] = make_float4(0.f, 0.f, 0.f, 0.f);
#define DSTEP(dd, FIELD, ARR) { const float4 wv = Wp[(dd)*4 + e4]; \
        _Pragma("unroll") \
        for (int bb = 0; bb < BB; ++bb) { const float xs = ARR[bb].FIELD; \
            v[bb].x += xs*wv.x; v[bb].y += xs*wv.y; \
            v[bb].z += xs*wv.z; v[bb].w += xs*wv.w; } }
        DSTEP(0, x, xa) DSTEP(1, y, xa) DSTEP(2, z, xa) DSTEP(3, w, xa)
        DSTEP(4, x, xc) DSTEP(5, y, xc) DSTEP(6, z, xc) DSTEP(7, w, xc)
#undef DSTEP
#pragma unroll
        for (int bb = 0; bb < BB; ++bb) {
            uint2 pk;
            pk.x = bf16_rne(v[bb].x) | (bf16_rne(v[bb].y) << 16);
            pk.y = bf16_rne(v[bb].z) | (bf16_rne(v[bb].w) << 16);
            *(uint2*)&pl[bb][i][e4 * 2] = pk;
            acc[bb].x += v[bb].x; acc[bb].y += v[bb].y;
            acc[bb].z += v[bb].z; acc[bb].w += v[bb].w;
        }
    }

    // ---- s0 = mean_i priors : reduce across quads (same e4) ----
#pragma unroll
    for (int bb = 0; bb < BB; ++bb) {
#pragma unroll
        for (int off = 4; off <= 32; off <<= 1) {
            acc[bb].x += __shfl_xor(acc[bb].x, off);
            acc[bb].y += __shfl_xor(acc[bb].y, off);
            acc[bb].z += __shfl_xor(acc[bb].z, off);
            acc[bb].w += __shfl_xor(acc[bb].w, off);
        }
        if (lane < 4) *(float4*)&red[bb][w * 16 + e4 * 4] = acc[bb];
    }
    __syncthreads();
    if (t < 16 * BB) {
        const int bb = t >> 4, e = t & 15;
        float s = 0.f;
#pragma unroll
        for (int q = 0; q < WAVES; ++q) s += red[bb][q * 16 + e];
        sv[bb][e] = s * (1.0f / (float)NI);
    }
    __syncthreads();

    // ---- squash(s0) -> outv (each thread keeps its e4 slice, all bb) ----
    float4 outv[BB];
#pragma unroll
    for (int bb = 0; bb < BB; ++bb) {
        float sq = 0.f;
#pragma unroll
        for (int e = 0; e < 16; ++e) { const float vv = sv[bb][e]; sq += vv * vv; }
        const float scale = sqrtf(sq) / (1.0f + sq);
        outv[bb].x = sv[bb][e4 * 4 + 0] * scale;
        outv[bb].y = sv[bb][e4 * 4 + 1] * scale;
        outv[bb].z = sv[bb][e4 * 4 + 2] * scale;
        outv[bb].w = sv[bb][e4 * 4 + 3] * scale;
    }

    // ---- routing iterations 1 and 2: single fused sweep per iteration ----
    for (int it = 1; it < 3; ++it) {
#pragma unroll
        for (int bb = 0; bb < BB; ++bb) {
            float4 pacc = make_float4(0.f, 0.f, 0.f, 0.f);
            float  lsum = 0.f;
#pragma unroll
            for (int k = 0; k < ITEMS; ++k) {
                const int i = iq + k * QUADS;
                const uint2 pk = *(const uint2*)&pl[bb][i][e4 * 2];
                const float vx = bf_lo(pk.x), vy = bf_hi(pk.x);
                const float vz = bf_lo(pk.y), vw = bf_hi(pk.y);
                float part = vx * outv[bb].x + vy * outv[bb].y
                           + vz * outv[bb].z + vw * outv[bb].w;
                part += __shfl_xor(part, 1);   // quad reduce: full dot over 16 E
                part += __shfl_xor(part, 2);
                const float l = (it == 1) ? part : (lg[bb][k] + part);
                lg[bb][k] = l;
                const float wgt = __expf(l);   // no max-sub: |l| <~ 40, safe
                pacc.x += wgt * vx; pacc.y += wgt * vy;
                pacc.z += wgt * vz; pacc.w += wgt * vw;
                lsum += wgt;                   // quad-uniform
            }
#pragma unroll
            for (int off = 4; off <= 32; off <<= 1) {
                pacc.x += __shfl_xor(pacc.x, off);
                pacc.y += __shfl_xor(pacc.y, off);
                pacc.z += __shfl_xor(pacc.z, off);
                pacc.w += __shfl_xor(pacc.w, off);
                lsum   += __shfl_xor(lsum, off);
            }
            if (lane < 4) *(float4*)&red[bb][w * 16 + e4 * 4] = pacc;
            if (lane == 0) rsum[bb][w] = lsum;
        }
        __syncthreads();
        if (t < 16 * BB) {
            const int bb = t >> 4, e = t & 15;
            float s = 0.f;
#pragma unroll
            for (int q = 0; q < WAVES; ++q) s += red[bb][q * 16 + e];
            float L = 0.f;
#pragma unroll
            for (int q = 0; q < WAVES; ++q) L += rsum[bb][q];
            sv[bb][e] = s / L;
        }
        __syncthreads();

        if (it == 1) {
            // squash -> new outv for the next sweep
#pragma unroll
            for (int bb = 0; bb < BB; ++bb) {
                float sq = 0.f;
#pragma unroll
                for (int e = 0; e < 16; ++e) { const float vv = sv[bb][e]; sq += vv * vv; }
                const float scale = sqrtf(sq) / (1.0f + sq);
                outv[bb].x = sv[bb][e4 * 4 + 0] * scale;
                outv[bb].y = sv[bb][e4 * 4 + 1] * scale;
                outv[bb].z = sv[bb][e4 * 4 + 2] * scale;
                outv[bb].w = sv[bb][e4 * 4 + 3] * scale;
            }
        }
    }

    // ---- final squash + write out[o, b0+bb, 0, 0, :] ----
    if (t < 16 * BB) {
        const int bb = t >> 4, e = t & 15;
        float sq = 0.f;
#pragma unroll
        for (int ee = 0; ee < 16; ++ee) { const float vv = sv[bb][ee]; sq += vv * vv; }
        const float scale = sqrtf(sq) / (1.0f + sq);
        out[((size_t)o * BATCH + b0 + bb) * NE + e] = sv[bb][e] * scale;
    }
}

extern "C" void kernel_launch(void* const* d_in, const int* in_sizes, int n_in,
                              void* d_out, int out_size, void* d_ws, size_t ws_size,
                              hipStream_t stream) {
    const float* x  = (const float*)d_in[0];
    const float* Wt = (const float*)d_in[1];
    float* outp = (float*)d_out;
    caps_routing<<<dim3(NO * BPG), dim3(THREADS), 0, stream>>>(x, Wt, outp);
}

// Round 13
// 171.243 us; speedup vs baseline: 2.0230x; 1.2649x over previous
//
#include <hip/hip_runtime.h>

#define BATCH 512
#define NI 1152
#define ND 8
#define NO 10
#define NE 16

constexpr int THREADS = 512;
constexpr int WAVES   = THREADS / 64;   // 8
constexpr int QUADS   = THREADS / 4;    // 128 i-rows per sweep
constexpr int ITEMS   = NI / QUADS;     // 9 (exact: 1152 = 128*9)
constexpr int BB      = 2;              // batch elements per block (W reuse)
constexpr int BPG     = BATCH / BB;     // 256 blocks per out-capsule

// Best measured structure (r7, 121us): 512 thr, BB=2, priors bf16 in LDS
// (74 KB -> 2 blocks/CU = 16 waves). r11 falsified bigger blocks (768thr:
// only ~1 blk resident, 185us). r7's residual: latency-bound at VALUBusy
// 51% with VGPR=64 -- the RA targets the 8-wave/SIMD tier although LDS
// caps us at 4 waves/SIMD, leaving ~64 VGPR/thread unused and only a
// shallow W-load pipeline.
//
// This round (single change): explicit W double-buffer wv[2][8] in the
// einsum k-loop -- next k's 8 W float4 loads issued before current k's
// FMAs. Static indices (full unroll, cur=k&1). Raises live regs to ~110
// < 128 cap (launch_bounds(512,4)); x deliberately NOT double-buffered
// (would exceed 128 -> r2/r8 spill catastrophe).
//
// Priors bf16 in LDS (storage only, fp32 math, RNE pack). Fused routing
// sweep (r5-r8, absmax 9.8e-3): no max-sub (|logit| <~ 40 << 88), one
// LDS pass per iter accumulating sum(exp(l)*p), sum(exp(l)).

__device__ __forceinline__ unsigned int bf16_rne(float f) {
    const unsigned int u = __builtin_bit_cast(unsigned int, f);
    return (u + 0x7fffu + ((u >> 16) & 1u)) >> 16;
}
__device__ __forceinline__ float bf_lo(unsigned int u) {
    return __builtin_bit_cast(float, u << 16);
}
__device__ __forceinline__ float bf_hi(unsigned int u) {
    return __builtin_bit_cast(float, u & 0xffff0000u);
}

__global__ __launch_bounds__(THREADS, 4)
void caps_routing(const float* __restrict__ x,
                  const float* __restrict__ Wt,
                  float* __restrict__ out)
{
    const int o  = blockIdx.x / BPG;
    const int b0 = (blockIdx.x % BPG) * BB;

    __shared__ __align__(16) unsigned int pl[BB][NI][NE / 2]; // bf16x2, 73728 B
    __shared__ __align__(16) float red[BB][WAVES * 16];       // 1 KiB
    __shared__ float sv[BB][16];
    __shared__ float rsum[BB][WAVES];

    const int t    = threadIdx.x;
    const int lane = t & 63;
    const int w    = t >> 6;
    const int e4   = t & 3;     // which float4 of the 16-wide E dim
    const int iq   = t >> 2;    // i-quad id, i = iq + k*QUADS

    const float* xb = x  + (size_t)b0 * (NI * ND);
    const float* Wo = Wt + (size_t)o * ((size_t)NI * ND * NE);

    float lg[BB][ITEMS];     // logits: quad-uniform (live only in routing)
    float4 acc[BB];
#pragma unroll
    for (int bb = 0; bb < BB; ++bb) acc[bb] = make_float4(0.f, 0.f, 0.f, 0.f);

    // ---- priors = x[b,i,:] @ W[o,i,:,:] -> LDS(bf16), fused iter-0 sum ----
    // W double-buffer: wv[cur] consumed while wv[nxt] loads are in flight.
    float4 wv[2][8];
    {
        const float4* Wp = (const float4*)(Wo + (size_t)iq * (ND * NE));
#pragma unroll
        for (int dd = 0; dd < 8; ++dd) wv[0][dd] = Wp[dd * 4 + e4];
    }
#pragma unroll
    for (int k = 0; k < ITEMS; ++k) {
        const int cur = k & 1, nxt = cur ^ 1;
        if (k + 1 < ITEMS) {   // issue next k's W loads FIRST (async, vmcnt)
            const float4* Wp =
                (const float4*)(Wo + (size_t)(iq + (k + 1) * QUADS) * (ND * NE));
#pragma unroll
            for (int dd = 0; dd < 8; ++dd) wv[nxt][dd] = Wp[dd * 4 + e4];
        }
        const int i = iq + k * QUADS;
        float4 xa[BB], xc[BB];
#pragma unroll
        for (int bb = 0; bb < BB; ++bb) {
            const float* xr = xb + (size_t)bb * (NI * ND) + (size_t)i * ND;
            xa[bb] = *(const float4*)(xr);
            xc[bb] = *(const float4*)(xr + 4);
        }
        float4 v[BB];
#pragma unroll
        for (int bb = 0; bb < BB; ++bb) v[bb] = make_float4(0.f, 0.f, 0.f, 0.f);
#define DSTEP(dd, FIELD, ARR) { const float4 w4 = wv[cur][dd]; \
        _Pragma("unroll") \
        for (int bb = 0; bb < BB; ++bb) { const float xs = ARR[bb].FIELD; \
            v[bb].x += xs*w4.x; v[bb].y += xs*w4.y; \
            v[bb].z += xs*w4.z; v[bb].w += xs*w4.w; } }
        DSTEP(0, x, xa) DSTEP(1, y, xa) DSTEP(2, z, xa) DSTEP(3, w, xa)
        DSTEP(4, x, xc) DSTEP(5, y, xc) DSTEP(6, z, xc) DSTEP(7, w, xc)
#undef DSTEP
#pragma unroll
        for (int bb = 0; bb < BB; ++bb) {
            uint2 pk;
            pk.x = bf16_rne(v[bb].x) | (bf16_rne(v[bb].y) << 16);
            pk.y = bf16_rne(v[bb].z) | (bf16_rne(v[bb].w) << 16);
            *(uint2*)&pl[bb][i][e4 * 2] = pk;
            acc[bb].x += v[bb].x; acc[bb].y += v[bb].y;
            acc[bb].z += v[bb].z; acc[bb].w += v[bb].w;
        }
    }

    // ---- s0 = mean_i priors : reduce across quads (same e4) ----
#pragma unroll
    for (int bb = 0; bb < BB; ++bb) {
#pragma unroll
        for (int off = 4; off <= 32; off <<= 1) {
            acc[bb].x += __shfl_xor(acc[bb].x, off);
            acc[bb].y += __shfl_xor(acc[bb].y, off);
            acc[bb].z += __shfl_xor(acc[bb].z, off);
            acc[bb].w += __shfl_xor(acc[bb].w, off);
        }
        if (lane < 4) *(float4*)&red[bb][w * 16 + e4 * 4] = acc[bb];
    }
    __syncthreads();
    if (t < 16 * BB) {
        const int bb = t >> 4, e = t & 15;
        float s = 0.f;
#pragma unroll
        for (int q = 0; q < WAVES; ++q) s += red[bb][q * 16 + e];
        sv[bb][e] = s * (1.0f / (float)NI);
    }
    __syncthreads();

    // ---- squash(s0) -> outv (each thread keeps its e4 slice, all bb) ----
    float4 outv[BB];
#pragma unroll
    for (int bb = 0; bb < BB; ++bb) {
        float sq = 0.f;
#pragma unroll
        for (int e = 0; e < 16; ++e) { const float vv = sv[bb][e]; sq += vv * vv; }
        const float scale = sqrtf(sq) / (1.0f + sq);
        outv[bb].x = sv[bb][e4 * 4 + 0] * scale;
        outv[bb].y = sv[bb][e4 * 4 + 1] * scale;
        outv[bb].z = sv[bb][e4 * 4 + 2] * scale;
        outv[bb].w = sv[bb][e4 * 4 + 3] * scale;
    }

    // ---- routing iterations 1 and 2: single fused sweep per iteration ----
    for (int it = 1; it < 3; ++it) {
#pragma unroll
        for (int bb = 0; bb < BB; ++bb) {
            float4 pacc = make_float4(0.f, 0.f, 0.f, 0.f);
            float  lsum = 0.f;
#pragma unroll
            for (int k = 0; k < ITEMS; ++k) {
                const int i = iq + k * QUADS;
                const uint2 pk = *(const uint2*)&pl[bb][i][e4 * 2];
                const float vx = bf_lo(pk.x), vy = bf_hi(pk.x);
                const float vz = bf_lo(pk.y), vw = bf_hi(pk.y);
                float part = vx * outv[bb].x + vy * outv[bb].y
                           + vz * outv[bb].z + vw * outv[bb].w;
                part += __shfl_xor(part, 1);   // quad reduce: full dot over 16 E
                part += __shfl_xor(part, 2);
                const float l = (it == 1) ? part : (lg[bb][k] + part);
                lg[bb][k] = l;
                const float wgt = __expf(l);   // no max-sub: |l| <~ 40, safe
                pacc.x += wgt * vx; pacc.y += wgt * vy;
                pacc.z += wgt * vz; pacc.w += wgt * vw;
                lsum += wgt;                   // quad-uniform
            }
#pragma unroll
            for (int off = 4; off <= 32; off <<= 1) {
                pacc.x += __shfl_xor(pacc.x, off);
                pacc.y += __shfl_xor(pacc.y, off);
                pacc.z += __shfl_xor(pacc.z, off);
                pacc.w += __shfl_xor(pacc.w, off);
                lsum   += __shfl_xor(lsum, off);
            }
            if (lane < 4) *(float4*)&red[bb][w * 16 + e4 * 4] = pacc;
            if (lane == 0) rsum[bb][w] = lsum;
        }
        __syncthreads();
        if (t < 16 * BB) {
            const int bb = t >> 4, e = t & 15;
            float s = 0.f;
#pragma unroll
            for (int q = 0; q < WAVES; ++q) s += red[bb][q * 16 + e];
            float L = 0.f;
#pragma unroll
            for (int q = 0; q < WAVES; ++q) L += rsum[bb][q];
            sv[bb][e] = s / L;
        }
        __syncthreads();

        if (it == 1) {
            // squash -> new outv for the next sweep
#pragma unroll
            for (int bb = 0; bb < BB; ++bb) {
                float sq = 0.f;
#pragma unroll
                for (int e = 0; e < 16; ++e) { const float vv = sv[bb][e]; sq += vv * vv; }
                const float scale = sqrtf(sq) / (1.0f + sq);
                outv[bb].x = sv[bb][e4 * 4 + 0] * scale;
                outv[bb].y = sv[bb][e4 * 4 + 1] * scale;
                outv[bb].z = sv[bb][e4 * 4 + 2] * scale;
                outv[bb].w = sv[bb][e4 * 4 + 3] * scale;
            }
        }
    }

    // ---- final squash + write out[o, b0+bb, 0, 0, :] ----
    if (t < 16 * BB) {
        const int bb = t >> 4, e = t & 15;
        float sq = 0.f;
#pragma unroll
        for (int ee = 0; ee < 16; ++ee) { const float vv = sv[bb][ee]; sq += vv * vv; }
        const float scale = sqrtf(sq) / (1.0f + sq);
        out[((size_t)o * BATCH + b0 + bb) * NE + e] = sv[bb][e] * scale;
    }
}

extern "C" void kernel_launch(void* const* d_in, const int* in_sizes, int n_in,
                              void* d_out, int out_size, void* d_ws, size_t ws_size,
                              hipStream_t stream) {
    const float* x  = (const float*)d_in[0];
    const float* Wt = (const float*)d_in[1];
    float* outp = (float*)d_out;
    caps_routing<<<dim3(NO * BPG), dim3(THREADS), 0, stream>>>(x, Wt, outp);
}